// Round 1
// baseline (267.107 us; speedup 1.0000x reference)
//
#include <hip/hip_runtime.h>

#define T_    8192
#define C_    1024
#define TCH   8            // timesteps per chunk (one K2 wave handles one chunk)
#define NCH   (T_ / TCH)   // 1024 chunks
#define SBS   8            // chunks per superblock (k_sumscan block granularity)
#define NSB   (NCH / SBS)  // 128 superblocks
#define BATCH 4            // timesteps per batched variance-reduce in K2

// ---------------------------------------------------------------------------
// k_sumscan: fused chunk-sum + within-superblock exclusive scan.
// Block (sb, b): 64 timesteps x 1024 channels (256 KB contiguous read).
// Thread owns 4 channels (float4). Writes S[b][ch][c] = exclusive prefix of
// chunk sums within the superblock, and S2[b][sb][c] = superblock total.
// Replaces the old k_chunk_sums + k_scan_a pair (saves a 32 MB S round-trip).
// ---------------------------------------------------------------------------
__global__ __launch_bounds__(256) void k_sumscan(const float* __restrict__ x,
                                                 float* __restrict__ S,
                                                 float* __restrict__ S2) {
    const int sb = blockIdx.x;
    const int b  = blockIdx.y;
    const int c  = threadIdx.x * 4;
    const float* xp = x + ((size_t)(b * T_ + sb * SBS * TCH) * C_ + c);
    float* Sp = S + ((size_t)(b * NCH + sb * SBS) * C_ + c);
    float4 run = make_float4(0.f, 0.f, 0.f, 0.f);
#pragma unroll
    for (int j = 0; j < SBS; ++j) {
        *(float4*)(Sp + (size_t)j * C_) = run;   // exclusive within superblock
        float4 v[TCH];
#pragma unroll
        for (int i = 0; i < TCH; ++i)
            v[i] = *(const float4*)(xp + (size_t)(j * TCH + i) * C_);
#pragma unroll
        for (int i = 0; i < TCH; ++i) {
            run.x += v[i].x; run.y += v[i].y; run.z += v[i].z; run.w += v[i].w;
        }
    }
    *(float4*)(S2 + ((size_t)(b * NSB + sb) * C_ + c)) = run;
}

// ---------------------------------------------------------------------------
// k_scan_b: in-place exclusive scan of S2 across the NSB superblocks, per
// (b,c). B*C = 4096 threads; 2 MB buffer, L2/L3-resident, pipelined unroll.
// ---------------------------------------------------------------------------
__global__ __launch_bounds__(256) void k_scan_b(float* __restrict__ S2) {
    const int idx = blockIdx.x * 256 + threadIdx.x;   // 0 .. B*C-1
    const int c = idx & (C_ - 1);
    const int b = idx >> 10;
    float* p = S2 + ((size_t)b * NSB * C_ + c);
    float run = 0.f;
#pragma unroll 8
    for (int j = 0; j < NSB; ++j) {
        float v = p[(size_t)j * C_];
        p[(size_t)j * C_] = run;
        run += v;
    }
}

// ---------------------------------------------------------------------------
// k_norm: block = 256 thr = 4 waves; wave w -> chunk ch = blockIdx.x*4 + w.
// Lane owns 16 channels (cq = q*256 + lane*4). prefix = S2 + S.
// The chunk's 8 timesteps are processed in two batches of 4: compute xc +
// per-lane partial sq for 4 timesteps (xc kept in registers), then run 4
// INDEPENDENT 6-step butterflies (latencies overlap) + 4 v_rsq, then store.
// This amortizes the serial shuffle-reduce chain 4x vs per-timestep reduce.
// ---------------------------------------------------------------------------
__global__ __launch_bounds__(256, 3) void k_norm(const float* __restrict__ x,
                                                 const float* __restrict__ S,
                                                 const float* __restrict__ S2,
                                                 const float* __restrict__ w,
                                                 float* __restrict__ out) {
    const int wave = threadIdx.x >> 6;
    const int lane = threadIdx.x & 63;
    const int ch   = blockIdx.x * 4 + wave;
    const int b    = blockIdx.y;
    const int cb   = lane * 4;

    float4 run[4], wt[4];
    const float* Pp  = S  + (size_t)(b * NCH + ch) * C_;
    const float* P2p = S2 + (size_t)(b * NSB + (ch / SBS)) * C_;
#pragma unroll
    for (int q = 0; q < 4; ++q) {
        float4 a  = *(const float4*)(Pp  + q * 256 + cb);
        float4 bb = *(const float4*)(P2p + q * 256 + cb);
        run[q] = make_float4(a.x + bb.x, a.y + bb.y, a.z + bb.z, a.w + bb.w);
        wt[q]  = *(const float4*)(w + q * 256 + cb);
    }

    const int t0 = ch * TCH;
    const float* xp = x   + (size_t)(b * T_ + t0) * C_;
    float*       op = out + (size_t)(b * T_ + t0) * C_;
    const float invC = 1.0f / (float)C_;

#pragma unroll
    for (int h = 0; h < TCH / BATCH; ++h) {
        float4 xc[BATCH][4];
        float  sq[BATCH];

        // ---- batch pass A: load, accumulate prefix, center, partial sq ----
#pragma unroll
        for (int i = 0; i < BATCH; ++i) {
            const int tt = t0 + h * BATCH + i;
            const float m = (tt == 0) ? 0.0f
                                      : __builtin_amdgcn_rcpf((float)(tt + 1));
            float s = 0.f;
#pragma unroll
            for (int q = 0; q < 4; ++q) {
                float4 v = *(const float4*)(xp + (size_t)(h * BATCH + i) * C_
                                               + q * 256 + cb);
                run[q].x += v.x; float a0 = v.x - run[q].x * m; s += a0 * a0;
                run[q].y += v.y; float a1 = v.y - run[q].y * m; s += a1 * a1;
                run[q].z += v.z; float a2 = v.z - run[q].z * m; s += a2 * a2;
                run[q].w += v.w; float a3 = v.w - run[q].w * m; s += a3 * a3;
                xc[i][q] = make_float4(a0, a1, a2, a3);
            }
            sq[i] = s;
        }

        // ---- batched butterfly: 4 independent 6-deep chains overlap ----
#pragma unroll
        for (int off = 32; off; off >>= 1) {
#pragma unroll
            for (int i = 0; i < BATCH; ++i)
                sq[i] += __shfl_xor(sq[i], off, 64);
        }

        float scale[BATCH];
#pragma unroll
        for (int i = 0; i < BATCH; ++i)
            scale[i] = __builtin_amdgcn_rsqf(sq[i] * invC + 1e-5f);

        // ---- batch pass C: scale + store ----
#pragma unroll
        for (int i = 0; i < BATCH; ++i) {
#pragma unroll
            for (int q = 0; q < 4; ++q) {
                float4 o;
                o.x = wt[q].x * xc[i][q].x * scale[i];
                o.y = wt[q].y * xc[i][q].y * scale[i];
                o.z = wt[q].z * xc[i][q].z * scale[i];
                o.w = wt[q].w * xc[i][q].w * scale[i];
                *(float4*)(op + (size_t)(h * BATCH + i) * C_ + q * 256 + cb) = o;
            }
        }
    }
}

extern "C" void kernel_launch(void* const* d_in, const int* in_sizes, int n_in,
                              void* d_out, int out_size, void* d_ws, size_t ws_size,
                              hipStream_t stream) {
    const float* x = (const float*)d_in[0];
    const float* w = (const float*)d_in[1];
    float* out = (float*)d_out;

    const int B = in_sizes[0] / (T_ * C_);            // 4

    float* S  = (float*)d_ws;                         // B*NCH*C floats = 16 MB
    float* S2 = S + (size_t)B * NCH * C_;             // B*NSB*C floats = 2 MB

    dim3 g1(NSB, B);                                  // 512 blocks
    k_sumscan<<<g1, 256, 0, stream>>>(x, S, S2);

    const int nb = B * C_;                            // 4096 threads
    k_scan_b<<<nb / 256, 256, 0, stream>>>(S2);

    dim3 g2(NCH / 4, B);                              // 1024 blocks
    k_norm<<<g2, 256, 0, stream>>>(x, S, S2, w, out);
}

// Round 4
// 261.006 us; speedup vs baseline: 1.0234x; 1.0234x over previous
//
#include <hip/hip_runtime.h>

#define T_    8192
#define C_    1024
#define TCH   16           // timesteps per chunk (one k_norm wave per chunk)
#define NCH   (T_ / TCH)   // 512 chunks
#define SBS   4            // chunks per superblock (k_sumscan granularity)
#define NSB   (NCH / SBS)  // 128 superblocks
#define BATCH 4            // timesteps per batched variance-reduce in k_norm

// native 16B vector type: __builtin_nontemporal_store needs ext_vector_type,
// not HIP_vector_type<float,4>
typedef float v4f __attribute__((ext_vector_type(4)));

// ---------------------------------------------------------------------------
// k_sumscan: fused chunk-sum + within-superblock exclusive scan.
// Block (sb, b): 64 timesteps x 1024 channels. Thread owns 4 channels.
// Writes S[b][ch][c] = exclusive prefix of chunk sums within superblock,
// S2[b][sb][c] = superblock total.
// ---------------------------------------------------------------------------
__global__ __launch_bounds__(256) void k_sumscan(const float* __restrict__ x,
                                                 float* __restrict__ S,
                                                 float* __restrict__ S2) {
    const int sb = blockIdx.x;
    const int b  = blockIdx.y;
    const int c  = threadIdx.x * 4;
    const float* xp = x + ((size_t)(b * T_ + sb * SBS * TCH) * C_ + c);
    float* Sp = S + ((size_t)(b * NCH + sb * SBS) * C_ + c);
    float4 run = make_float4(0.f, 0.f, 0.f, 0.f);
#pragma unroll
    for (int j = 0; j < SBS; ++j) {
        *(float4*)(Sp + (size_t)j * C_) = run;   // exclusive within superblock
#pragma unroll
        for (int hh = 0; hh < 2; ++hh) {         // 16 rows in 2 batches of 8
            float4 v[8];
#pragma unroll
            for (int i = 0; i < 8; ++i)
                v[i] = *(const float4*)(xp + (size_t)(j * TCH + hh * 8 + i) * C_);
#pragma unroll
            for (int i = 0; i < 8; ++i) {
                run.x += v[i].x; run.y += v[i].y;
                run.z += v[i].z; run.w += v[i].w;
            }
        }
    }
    *(float4*)(S2 + ((size_t)(b * NSB + sb) * C_ + c)) = run;
}

// ---------------------------------------------------------------------------
// k_scan2: exclusive scan of S2 across NSB=128 superblocks per (b,c),
// parallelized: one WAVE per (b,c); lane L owns rows L and 64+L. Two 64-wide
// Hillis-Steele shuffle scans replace the old 128-step serial pointer chase.
// Loads are uncoalesced (stride 4 KB) but the 2 MB buffer is L2-resident.
// ---------------------------------------------------------------------------
__global__ __launch_bounds__(256) void k_scan2(float* __restrict__ S2, int B) {
    const int wid  = blockIdx.x * 4 + (threadIdx.x >> 6);   // 0 .. B*C-1
    const int lane = threadIdx.x & 63;
    if (wid >= B * C_) return;
    const int b = wid >> 10;
    const int c = wid & (C_ - 1);
    float* base = S2 + ((size_t)b * NSB * C_ + c);

    float v0 = base[(size_t)lane * C_];
    float v1 = base[(size_t)(64 + lane) * C_];

    // inclusive scan of v0 across lanes
#pragma unroll
    for (int off = 1; off < 64; off <<= 1) {
        float t = __shfl_up(v0, off, 64);
        if (lane >= off) v0 += t;
    }
    const float total0 = __shfl(v0, 63, 64);

    // inclusive scan of v1 across lanes, then add first-half total
#pragma unroll
    for (int off = 1; off < 64; off <<= 1) {
        float t = __shfl_up(v1, off, 64);
        if (lane >= off) v1 += t;
    }
    v1 += total0;

    // convert to exclusive and store back
    float e0 = __shfl_up(v0, 1, 64);
    if (lane == 0) e0 = 0.f;
    float e1 = __shfl_up(v1, 1, 64);
    if (lane == 0) e1 = total0;
    base[(size_t)lane * C_]        = e0;
    base[(size_t)(64 + lane) * C_] = e1;
}

// ---------------------------------------------------------------------------
// k_norm: block = 256 thr = 4 waves; wave w -> chunk ch = blockIdx.x*4 + w
// (16 timesteps). Lane owns 16 channels (cq = q*256 + lane*4).
// prefix = S2 + S loaded once; 4 batches of 4 timesteps, each batch keeps xc
// in registers, then 4 INDEPENDENT 6-step butterflies overlap, 4 v_rsq,
// then nontemporal stores (out is streaming; keep L3 free for x re-read).
// ---------------------------------------------------------------------------
__global__ __launch_bounds__(256) void k_norm(const float* __restrict__ x,
                                              const float* __restrict__ S,
                                              const float* __restrict__ S2,
                                              const float* __restrict__ w,
                                              float* __restrict__ out) {
    const int wave = threadIdx.x >> 6;
    const int lane = threadIdx.x & 63;
    const int ch   = blockIdx.x * 4 + wave;
    const int b    = blockIdx.y;
    const int cb   = lane * 4;

    float4 run[4], wt[4];
    const float* Pp  = S  + (size_t)(b * NCH + ch) * C_;
    const float* P2p = S2 + (size_t)(b * NSB + (ch / SBS)) * C_;
#pragma unroll
    for (int q = 0; q < 4; ++q) {
        float4 a  = *(const float4*)(Pp  + q * 256 + cb);
        float4 bb = *(const float4*)(P2p + q * 256 + cb);
        run[q] = make_float4(a.x + bb.x, a.y + bb.y, a.z + bb.z, a.w + bb.w);
        wt[q]  = *(const float4*)(w + q * 256 + cb);
    }

    const int t0 = ch * TCH;
    const float* xp = x   + (size_t)(b * T_ + t0) * C_;
    float*       op = out + (size_t)(b * T_ + t0) * C_;
    const float invC = 1.0f / (float)C_;

#pragma unroll
    for (int h = 0; h < TCH / BATCH; ++h) {
        float4 xc[BATCH][4];
        float  sq[BATCH];

        // ---- load, accumulate prefix, center, per-lane partial sq ----
#pragma unroll
        for (int i = 0; i < BATCH; ++i) {
            const int tt = t0 + h * BATCH + i;
            const float m = (tt == 0) ? 0.0f
                                      : __builtin_amdgcn_rcpf((float)(tt + 1));
            float s = 0.f;
#pragma unroll
            for (int q = 0; q < 4; ++q) {
                float4 v = *(const float4*)(xp + (size_t)(h * BATCH + i) * C_
                                               + q * 256 + cb);
                run[q].x += v.x; float a0 = v.x - run[q].x * m; s += a0 * a0;
                run[q].y += v.y; float a1 = v.y - run[q].y * m; s += a1 * a1;
                run[q].z += v.z; float a2 = v.z - run[q].z * m; s += a2 * a2;
                run[q].w += v.w; float a3 = v.w - run[q].w * m; s += a3 * a3;
                xc[i][q] = make_float4(a0, a1, a2, a3);
            }
            sq[i] = s;
        }

        // ---- 4 independent 6-deep butterflies (latencies overlap) ----
#pragma unroll
        for (int off = 32; off; off >>= 1) {
#pragma unroll
            for (int i = 0; i < BATCH; ++i)
                sq[i] += __shfl_xor(sq[i], off, 64);
        }

        float scale[BATCH];
#pragma unroll
        for (int i = 0; i < BATCH; ++i)
            scale[i] = __builtin_amdgcn_rsqf(sq[i] * invC + 1e-5f);

        // ---- scale + nontemporal store (native vec type for the builtin) ----
#pragma unroll
        for (int i = 0; i < BATCH; ++i) {
#pragma unroll
            for (int q = 0; q < 4; ++q) {
                v4f o;
                o.x = wt[q].x * xc[i][q].x * scale[i];
                o.y = wt[q].y * xc[i][q].y * scale[i];
                o.z = wt[q].z * xc[i][q].z * scale[i];
                o.w = wt[q].w * xc[i][q].w * scale[i];
                __builtin_nontemporal_store(o,
                    (v4f*)(op + (size_t)(h * BATCH + i) * C_ + q * 256 + cb));
            }
        }
    }
}

extern "C" void kernel_launch(void* const* d_in, const int* in_sizes, int n_in,
                              void* d_out, int out_size, void* d_ws, size_t ws_size,
                              hipStream_t stream) {
    const float* x = (const float*)d_in[0];
    const float* w = (const float*)d_in[1];
    float* out = (float*)d_out;

    const int B = in_sizes[0] / (T_ * C_);            // 4

    float* S  = (float*)d_ws;                         // B*NCH*C floats = 8 MB
    float* S2 = S + (size_t)B * NCH * C_;             // B*NSB*C floats = 2 MB

    dim3 g1(NSB, B);                                  // 512 blocks
    k_sumscan<<<g1, 256, 0, stream>>>(x, S, S2);

    const int nwaves = B * C_;                        // 4096 waves
    k_scan2<<<nwaves / 4, 256, 0, stream>>>(S2, B);

    dim3 g2(NCH / 4, B);                              // 512 blocks
    k_norm<<<g2, 256, 0, stream>>>(x, S, S2, w, out);
}